// Round 1
// baseline (2648.518 us; speedup 1.0000x reference)
//
#include <hip/hip_runtime.h>
#include <hip/hip_bf16.h>
#include <stdint.h>

#define B_TOT 262144
#define DIN 35
#define HD 64

__device__ __forceinline__ float bf2f(uint32_t u)   { return __uint_as_float(u << 16); }
__device__ __forceinline__ float bfhi2f(uint32_t u) { return __uint_as_float(u & 0xffff0000u); }
__device__ __forceinline__ uint32_t f2bf(float x) {
  uint32_t u = __float_as_uint(x);
  return (u + 0x7fffu + ((u >> 16) & 1u)) >> 16;   // RTN-even
}

// ---------------- GAT (both layers), wave-per-element ----------------
template<bool ELU>
__device__ __forceinline__ void gat_att(const float z[3], const int cnt[3][3],
                                        float as_l, float ad_l, float b_l, float hres[3])
{
  float ss[3], sd[3];
  #pragma unroll
  for (int n = 0; n < 3; ++n) { ss[n] = z[n] * as_l; sd[n] = z[n] * ad_l; }
  #pragma unroll
  for (int off = 32; off > 0; off >>= 1) {
    #pragma unroll
    for (int n = 0; n < 3; ++n) {
      ss[n] += __shfl_xor(ss[n], off, 64);
      sd[n] += __shfl_xor(sd[n], off, 64);
    }
  }
  #pragma unroll
  for (int i = 0; i < 3; ++i) {
    float ev[3]; float m = -1e30f;
    #pragma unroll
    for (int j = 0; j < 3; ++j) {
      float eij = ss[j] + sd[i];
      eij = eij > 0.f ? eij : 0.2f * eij;      // leaky_relu slope 0.2
      ev[j] = eij;
      m = (cnt[i][j] > 0 && eij > m) ? eij : m;
    }
    float p[3], s = 0.f;
    #pragma unroll
    for (int j = 0; j < 3; ++j) { p[j] = (float)cnt[i][j] * __expf(ev[j] - m); s += p[j]; }
    const float inv = 1.f / s;
    float v = (p[0] * z[0] + p[1] * z[1] + p[2] * z[2]) * inv + b_l;
    if (ELU) v = v > 0.f ? v : (__expf(v) - 1.f);
    hres[i] = v;
  }
}

__global__ __launch_bounds__(256) void gat_kernel(
    const float* __restrict__ obs, const float* __restrict__ actn, const int* __restrict__ adj,
    const float* __restrict__ W1, const float* __restrict__ a1s, const float* __restrict__ a1d, const float* __restrict__ b1,
    const float* __restrict__ W2, const float* __restrict__ a2s, const float* __restrict__ a2d, const float* __restrict__ b2,
    uint16_t* __restrict__ hout)
{
  __shared__ float W1s[DIN * HD];
  __shared__ float W2s[HD * HD];
  __shared__ float xb[4][3][40];
  __shared__ float hb[4][3][HD];
  const int tid = threadIdx.x;
  for (int i = tid; i < DIN * HD; i += 256) W1s[i] = W1[i];
  for (int i = tid; i < HD * HD; i += 256) W2s[i] = W2[i];
  __syncthreads();
  const int lane = tid & 63;
  const int w = tid >> 6;
  const float a1s_l = a1s[lane], a1d_l = a1d[lane], b1_l = b1[lane];
  const float a2s_l = a2s[lane], a2d_l = a2d[lane], b2_l = b2[lane];
  const int gw = blockIdx.x * 4 + w;
  const int stride = gridDim.x * 4;
  for (int e = gw; e < B_TOT; e += stride) {
    // stage x = concat(obs[e].reshape(3,30), act[e].reshape(3,5)) -> xb[w][n][k]
    {
      const int l = lane;                       // 0..63 -> obs
      xb[w][l / 30][l % 30] = obs[e * 90 + l];
      const int l2 = lane + 64;
      if (l2 < 90)       xb[w][l2 / 30][l2 % 30] = obs[e * 90 + l2];
      else if (l2 < 105) { const int la = l2 - 90; xb[w][la / 5][30 + la % 5] = actn[e * 15 + la]; }
    }
    int cnt[3][3];
    #pragma unroll
    for (int i = 0; i < 3; ++i)
      #pragma unroll
      for (int j = 0; j < 3; ++j)
        cnt[i][j] = adj[e * 9 + j * 3 + i] + (i == j ? 1 : 0);   // adj^T + I
    __syncthreads();

    // z1[n][lane] = sum_k x[n][k] * W1[k][lane]
    float z[3] = {0.f, 0.f, 0.f};
    #pragma unroll
    for (int k = 0; k < DIN; ++k) {
      const float wv = W1s[k * 64 + lane];
      z[0] = fmaf(xb[w][0][k], wv, z[0]);
      z[1] = fmaf(xb[w][1][k], wv, z[1]);
      z[2] = fmaf(xb[w][2][k], wv, z[2]);
    }
    float h1[3];
    gat_att<true>(z, cnt, a1s_l, a1d_l, b1_l, h1);
    #pragma unroll
    for (int i = 0; i < 3; ++i) hb[w][i][lane] = h1[i];
    __syncthreads();

    // z2[n][lane] = sum_k h1[n][k] * W2[k][lane]
    float z2[3] = {0.f, 0.f, 0.f};
    #pragma unroll
    for (int k = 0; k < HD; ++k) {
      const float wv = W2s[k * 64 + lane];
      z2[0] = fmaf(hb[w][0][k], wv, z2[0]);
      z2[1] = fmaf(hb[w][1][k], wv, z2[1]);
      z2[2] = fmaf(hb[w][2][k], wv, z2[2]);
    }
    float h2[3];
    gat_att<false>(z2, cnt, a2s_l, a2d_l, b2_l, h2);
    #pragma unroll
    for (int i = 0; i < 3; ++i)
      hout[(size_t)e * 192 + i * 64 + lane] = (uint16_t)f2bf(h2[i]);
  }
}

// ---------------- MLP (Linear+LN+LReLU x2, Linear), lane-per-element ----------------
__global__ __launch_bounds__(64, 1) void mlp_kernel(
    const uint16_t* __restrict__ hin,
    const float* __restrict__ Wo1, const float* __restrict__ bo1,
    const float* __restrict__ g1,  const float* __restrict__ be1,
    const float* __restrict__ Wo2, const float* __restrict__ bo2,
    const float* __restrict__ g2,  const float* __restrict__ be2,
    const float* __restrict__ Wo3, const float* __restrict__ bo3,
    float* __restrict__ out)
{
  __shared__ uint32_t y1s[64 * 132];       // per-thread padded row: stride 132 dwords
  const int t = threadIdx.x;
  const int e = blockIdx.x * 64 + t;

  float y1[256];
  #pragma unroll
  for (int o = 0; o < 256; ++o) y1[o] = bo1[o];

  const uint16_t* hp = hin + (size_t)e * 192;
  #pragma unroll 1
  for (int kc = 0; kc < 24; ++kc) {
    const uint4 hv = *reinterpret_cast<const uint4*>(hp + kc * 8);
    float f[8];
    f[0] = bf2f(hv.x); f[1] = bfhi2f(hv.x);
    f[2] = bf2f(hv.y); f[3] = bfhi2f(hv.y);
    f[4] = bf2f(hv.z); f[5] = bfhi2f(hv.z);
    f[6] = bf2f(hv.w); f[7] = bfhi2f(hv.w);
    const float* wr = Wo1 + kc * 8 * 256;
    #pragma unroll
    for (int j = 0; j < 8; ++j)
      #pragma unroll
      for (int o = 0; o < 256; ++o)
        y1[o] = fmaf(f[j], wr[j * 256 + o], y1[o]);
  }
  // LayerNorm(256) + leaky_relu(0.01), pack bf16 pairs into LDS
  float s = 0.f;
  #pragma unroll
  for (int o = 0; o < 256; ++o) s += y1[o];
  const float mu = s * (1.f / 256.f);
  float vs = 0.f;
  #pragma unroll
  for (int o = 0; o < 256; ++o) { const float d = y1[o] - mu; vs = fmaf(d, d, vs); }
  const float r = rsqrtf(vs * (1.f / 256.f) + 1e-5f);
  #pragma unroll
  for (int o2 = 0; o2 < 128; ++o2) {
    float va = (y1[2 * o2]     - mu) * r * g1[2 * o2]     + be1[2 * o2];
    va = va > 0.f ? va : 0.01f * va;
    float vb = (y1[2 * o2 + 1] - mu) * r * g1[2 * o2 + 1] + be1[2 * o2 + 1];
    vb = vb > 0.f ? vb : 0.01f * vb;
    y1s[t * 132 + o2] = f2bf(va) | (f2bf(vb) << 16);
  }

  float y2[128];
  #pragma unroll
  for (int o = 0; o < 128; ++o) y2[o] = bo2[o];
  #pragma unroll 1
  for (int kc = 0; kc < 32; ++kc) {
    const uint4 yv = *reinterpret_cast<const uint4*>(&y1s[t * 132 + kc * 4]);
    float f[8];
    f[0] = bf2f(yv.x); f[1] = bfhi2f(yv.x);
    f[2] = bf2f(yv.y); f[3] = bfhi2f(yv.y);
    f[4] = bf2f(yv.z); f[5] = bfhi2f(yv.z);
    f[6] = bf2f(yv.w); f[7] = bfhi2f(yv.w);
    const float* wr = Wo2 + kc * 8 * 128;
    #pragma unroll
    for (int j = 0; j < 8; ++j)
      #pragma unroll
      for (int o = 0; o < 128; ++o)
        y2[o] = fmaf(f[j], wr[j * 128 + o], y2[o]);
  }
  // LayerNorm(128) + leaky_relu + final dot
  float s2 = 0.f;
  #pragma unroll
  for (int o = 0; o < 128; ++o) s2 += y2[o];
  const float mu2 = s2 * (1.f / 128.f);
  float vs2 = 0.f;
  #pragma unroll
  for (int o = 0; o < 128; ++o) { const float d = y2[o] - mu2; vs2 = fmaf(d, d, vs2); }
  const float r2 = rsqrtf(vs2 * (1.f / 128.f) + 1e-5f);
  float acc = bo3[0];
  #pragma unroll
  for (int o = 0; o < 128; ++o) {
    float v = (y2[o] - mu2) * r2 * g2[o] + be2[o];
    v = v > 0.f ? v : 0.01f * v;
    acc = fmaf(v, Wo3[o], acc);
  }
  out[e] = acc;
}

extern "C" void kernel_launch(void* const* d_in, const int* in_sizes, int n_in,
                              void* d_out, int out_size, void* d_ws, size_t ws_size,
                              hipStream_t stream) {
  const float* obs  = (const float*)d_in[0];
  const float* actn = (const float*)d_in[1];
  const int*   adj  = (const int*)d_in[2];
  const float* W1   = (const float*)d_in[3];
  const float* a1s  = (const float*)d_in[4];
  const float* a1d  = (const float*)d_in[5];
  const float* b1   = (const float*)d_in[6];
  const float* W2   = (const float*)d_in[7];
  const float* a2s  = (const float*)d_in[8];
  const float* a2d  = (const float*)d_in[9];
  const float* b2   = (const float*)d_in[10];
  const float* Wo1  = (const float*)d_in[11];
  const float* bo1  = (const float*)d_in[12];
  const float* g1   = (const float*)d_in[13];
  const float* be1  = (const float*)d_in[14];
  const float* Wo2  = (const float*)d_in[15];
  const float* bo2  = (const float*)d_in[16];
  const float* g2   = (const float*)d_in[17];
  const float* be2  = (const float*)d_in[18];
  const float* Wo3  = (const float*)d_in[19];
  const float* bo3  = (const float*)d_in[20];

  uint16_t* hws = (uint16_t*)d_ws;           // h: [B,192] bf16 = 100.7 MB
  float* outp = (float*)d_out;

  gat_kernel<<<1024, 256, 0, stream>>>(obs, actn, adj, W1, a1s, a1d, b1,
                                       W2, a2s, a2d, b2, hws);
  mlp_kernel<<<4096, 64, 0, stream>>>(hws, Wo1, bo1, g1, be1, Wo2, bo2,
                                      g2, be2, Wo3, bo3, outp);
}

// Round 2
// 926.080 us; speedup vs baseline: 2.8599x; 2.8599x over previous
//
#include <hip/hip_runtime.h>
#include <hip/hip_bf16.h>
#include <stdint.h>

#define B_TOT 262144
#define DIN 35
#define HD 64

typedef __attribute__((ext_vector_type(8))) short bf8v;
typedef __attribute__((ext_vector_type(4))) float f32x4;

__device__ __forceinline__ float bf2f(uint32_t u)   { return __uint_as_float(u << 16); }
__device__ __forceinline__ float bfhi2f(uint32_t u) { return __uint_as_float(u & 0xffff0000u); }
__device__ __forceinline__ uint32_t f2bf(float x) {
  uint32_t u = __float_as_uint(x);
  return (u + 0x7fffu + ((u >> 16) & 1u)) >> 16;   // RTN-even
}

// ---------------- weight prep: pack Wo1/Wo2 into MFMA fragment order ----------------
// frag layout (B-operand of 16x16x32, == A-operand of the transposed matrix):
//   value = W[ks*32 + (l>>4)*8 + e][t*16 + (l&15)]  stored at ((ks*T + t)*64 + l)*8 + e
__global__ __launch_bounds__(256) void prep_kernel(
    const float* __restrict__ Wo1, const float* __restrict__ Wo2,
    uint16_t* __restrict__ W1f, uint16_t* __restrict__ W2f)
{
  const int idx = blockIdx.x * 256 + threadIdx.x;
  if (idx < 6 * 16 * 64 * 8) {   // Wo1: 192x256
    const int e = idx & 7, l = (idx >> 3) & 63, t = (idx >> 9) & 15, ks = idx >> 13;
    const int k = ks * 32 + (l >> 4) * 8 + e, n = t * 16 + (l & 15);
    W1f[idx] = (uint16_t)f2bf(Wo1[k * 256 + n]);
  }
  if (idx < 8 * 8 * 64 * 8) {    // Wo2: 256x128
    const int e = idx & 7, l = (idx >> 3) & 63, t = (idx >> 9) & 7, ks = idx >> 12;
    const int k = ks * 32 + (l >> 4) * 8 + e, n = t * 16 + (l & 15);
    W2f[idx] = (uint16_t)f2bf(Wo2[k * 128 + n]);
  }
}

// ---------------- GAT (both layers), wave-per-element ----------------
template<bool ELU>
__device__ __forceinline__ void gat_att(const float z[3], const int cnt[3][3],
                                        float as_l, float ad_l, float b_l, float hres[3])
{
  float ss[3], sd[3];
  #pragma unroll
  for (int n = 0; n < 3; ++n) { ss[n] = z[n] * as_l; sd[n] = z[n] * ad_l; }
  #pragma unroll
  for (int off = 32; off > 0; off >>= 1) {
    #pragma unroll
    for (int n = 0; n < 3; ++n) {
      ss[n] += __shfl_xor(ss[n], off, 64);
      sd[n] += __shfl_xor(sd[n], off, 64);
    }
  }
  #pragma unroll
  for (int i = 0; i < 3; ++i) {
    float ev[3]; float m = -1e30f;
    #pragma unroll
    for (int j = 0; j < 3; ++j) {
      float eij = ss[j] + sd[i];
      eij = eij > 0.f ? eij : 0.2f * eij;      // leaky_relu slope 0.2
      ev[j] = eij;
      m = (cnt[i][j] > 0 && eij > m) ? eij : m;
    }
    float p[3], s = 0.f;
    #pragma unroll
    for (int j = 0; j < 3; ++j) { p[j] = (float)cnt[i][j] * __expf(ev[j] - m); s += p[j]; }
    const float inv = 1.f / s;
    float v = (p[0] * z[0] + p[1] * z[1] + p[2] * z[2]) * inv + b_l;
    if (ELU) v = v > 0.f ? v : (__expf(v) - 1.f);
    hres[i] = v;
  }
}

__global__ __launch_bounds__(256) void gat_kernel(
    const float* __restrict__ obs, const float* __restrict__ actn, const int* __restrict__ adj,
    const float* __restrict__ W1, const float* __restrict__ a1s, const float* __restrict__ a1d, const float* __restrict__ b1,
    const float* __restrict__ W2, const float* __restrict__ a2s, const float* __restrict__ a2d, const float* __restrict__ b2,
    uint16_t* __restrict__ hout)
{
  __shared__ float W1s[DIN * HD];
  __shared__ float W2s[HD * HD];
  __shared__ float xb[4][3][40];
  __shared__ float hb[4][3][HD];
  const int tid = threadIdx.x;
  for (int i = tid; i < DIN * HD; i += 256) W1s[i] = W1[i];
  for (int i = tid; i < HD * HD; i += 256) W2s[i] = W2[i];
  __syncthreads();
  const int lane = tid & 63;
  const int w = tid >> 6;
  const float a1s_l = a1s[lane], a1d_l = a1d[lane], b1_l = b1[lane];
  const float a2s_l = a2s[lane], a2d_l = a2d[lane], b2_l = b2[lane];
  const int gw = blockIdx.x * 4 + w;
  const int stride = gridDim.x * 4;
  for (int e = gw; e < B_TOT; e += stride) {
    // stage x = concat(obs[e].reshape(3,30), act[e].reshape(3,5)) -> xb[w][n][k]
    {
      const int l = lane;                       // 0..63 -> obs
      xb[w][l / 30][l % 30] = obs[e * 90 + l];
      const int l2 = lane + 64;
      if (l2 < 90)       xb[w][l2 / 30][l2 % 30] = obs[e * 90 + l2];
      else if (l2 < 105) { const int la = l2 - 90; xb[w][la / 5][30 + la % 5] = actn[e * 15 + la]; }
    }
    int cnt[3][3];
    #pragma unroll
    for (int i = 0; i < 3; ++i)
      #pragma unroll
      for (int j = 0; j < 3; ++j)
        cnt[i][j] = adj[e * 9 + j * 3 + i] + (i == j ? 1 : 0);   // adj^T + I
    // NOTE: xb/hb are per-wave buffers -> no __syncthreads needed; compiler
    // inserts lgkmcnt waits for the same-wave RAW dependencies.

    // z1[n][lane] = sum_k x[n][k] * W1[k][lane]
    float z[3] = {0.f, 0.f, 0.f};
    #pragma unroll
    for (int k = 0; k < DIN; ++k) {
      const float wv = W1s[k * 64 + lane];
      z[0] = fmaf(xb[w][0][k], wv, z[0]);
      z[1] = fmaf(xb[w][1][k], wv, z[1]);
      z[2] = fmaf(xb[w][2][k], wv, z[2]);
    }
    float h1[3];
    gat_att<true>(z, cnt, a1s_l, a1d_l, b1_l, h1);
    #pragma unroll
    for (int i = 0; i < 3; ++i) hb[w][i][lane] = h1[i];

    // z2[n][lane] = sum_k h1[n][k] * W2[k][lane]
    float z2[3] = {0.f, 0.f, 0.f};
    #pragma unroll
    for (int k = 0; k < HD; ++k) {
      const float wv = W2s[k * 64 + lane];
      z2[0] = fmaf(hb[w][0][k], wv, z2[0]);
      z2[1] = fmaf(hb[w][1][k], wv, z2[1]);
      z2[2] = fmaf(hb[w][2][k], wv, z2[2]);
    }
    float h2[3];
    gat_att<false>(z2, cnt, a2s_l, a2d_l, b2_l, h2);
    #pragma unroll
    for (int i = 0; i < 3; ++i)
      hout[(size_t)e * 192 + i * 64 + lane] = (uint16_t)f2bf(h2[i]);
  }
}

// ---------------- MLP via MFMA: 2 waves/block, 32 rows/wave ----------------
__global__ __launch_bounds__(128, 2) void mlp_kernel(
    const uint16_t* __restrict__ hin,
    const uint16_t* __restrict__ W1f, const uint16_t* __restrict__ W2f,
    const float* __restrict__ bo1, const float* __restrict__ g1, const float* __restrict__ be1,
    const float* __restrict__ bo2, const float* __restrict__ g2, const float* __restrict__ be2,
    const float* __restrict__ Wo3, const float* __restrict__ bo3,
    float* __restrict__ out)
{
  __shared__ __align__(16) uint16_t y1s[2][32][264];   // row stride 528B = 132 dwords (!= 0 mod 32)
  const int tid = threadIdx.x;
  const int w = tid >> 6, l = tid & 63;
  const int lg = l >> 4, lr = l & 15;
  const int row0 = blockIdx.x * 64 + w * 32;

  // ---- layer 1: Y1[32,256] = h[32,192] @ Wo1 + bo1
  f32x4 acc1[2][16];
  #pragma unroll
  for (int t = 0; t < 16; ++t) {
    const float b = bo1[t * 16 + lr];            // C col = t*16 + (l&15)
    acc1[0][t] = (f32x4){b, b, b, b};
    acc1[1][t] = (f32x4){b, b, b, b};
  }
  #pragma unroll
  for (int ks = 0; ks < 6; ++ks) {
    bf8v a[2];
    #pragma unroll
    for (int rt = 0; rt < 2; ++rt)               // A row = l&15, k = (l>>4)*8+e
      a[rt] = *reinterpret_cast<const bf8v*>(hin + (size_t)(row0 + rt * 16 + lr) * 192 + ks * 32 + lg * 8);
    const uint16_t* wp = W1f + ks * 16 * 512 + l * 8;
    #pragma unroll
    for (int t = 0; t < 16; ++t) {
      const bf8v b = *reinterpret_cast<const bf8v*>(wp + t * 512);
      acc1[0][t] = __builtin_amdgcn_mfma_f32_16x16x32_bf16(a[0], b, acc1[0][t], 0, 0, 0);
      acc1[1][t] = __builtin_amdgcn_mfma_f32_16x16x32_bf16(a[1], b, acc1[1][t], 0, 0, 0);
    }
  }
  // LN(256) + lrelu(0.01) -> bf16 -> LDS (transpose bounce)
  float g1v[16], be1v[16];
  #pragma unroll
  for (int t = 0; t < 16; ++t) { g1v[t] = g1[t * 16 + lr]; be1v[t] = be1[t * 16 + lr]; }
  #pragma unroll
  for (int rt = 0; rt < 2; ++rt) {
    float sm[4] = {0, 0, 0, 0}, sq[4] = {0, 0, 0, 0};
    #pragma unroll
    for (int t = 0; t < 16; ++t)
      #pragma unroll
      for (int r = 0; r < 4; ++r) { const float v = acc1[rt][t][r]; sm[r] += v; sq[r] = fmaf(v, v, sq[r]); }
    #pragma unroll
    for (int off = 1; off < 16; off <<= 1)
      #pragma unroll
      for (int r = 0; r < 4; ++r) {
        sm[r] += __shfl_xor(sm[r], off, 64);
        sq[r] += __shfl_xor(sq[r], off, 64);
      }
    float mu[4], rr[4];
    #pragma unroll
    for (int r = 0; r < 4; ++r) {
      mu[r] = sm[r] * (1.f / 256.f);
      rr[r] = rsqrtf(sq[r] * (1.f / 256.f) - mu[r] * mu[r] + 1e-5f);
    }
    #pragma unroll
    for (int t = 0; t < 16; ++t)
      #pragma unroll
      for (int r = 0; r < 4; ++r) {
        float v = (acc1[rt][t][r] - mu[r]) * rr[r] * g1v[t] + be1v[t];
        v = v > 0.f ? v : 0.01f * v;
        y1s[w][rt * 16 + lg * 4 + r][t * 16 + lr] = (uint16_t)f2bf(v);
      }
  }
  // ---- layer 2 (swapped operands): Y2^T[128,32] = Wo2^T @ Y1^T
  f32x4 acc2[2][8];
  #pragma unroll
  for (int t = 0; t < 8; ++t) {                  // D row = feature = t*16 + lg*4 + r
    const f32x4 bv = *reinterpret_cast<const f32x4*>(bo2 + t * 16 + lg * 4);
    acc2[0][t] = bv; acc2[1][t] = bv;
  }
  #pragma unroll
  for (int ks = 0; ks < 8; ++ks) {
    bf8v yb[2];
    #pragma unroll
    for (int rt = 0; rt < 2; ++rt)               // B col = batch row = l&15
      yb[rt] = *reinterpret_cast<const bf8v*>(&y1s[w][rt * 16 + lr][ks * 32 + lg * 8]);
    const uint16_t* wp = W2f + ks * 8 * 512 + l * 8;
    #pragma unroll
    for (int t = 0; t < 8; ++t) {
      const bf8v aw = *reinterpret_cast<const bf8v*>(wp + t * 512);
      acc2[0][t] = __builtin_amdgcn_mfma_f32_16x16x32_bf16(aw, yb[0], acc2[0][t], 0, 0, 0);
      acc2[1][t] = __builtin_amdgcn_mfma_f32_16x16x32_bf16(aw, yb[1], acc2[1][t], 0, 0, 0);
    }
  }
  // LN(128) + lrelu + final dot with Wo3; batch row = lr, features spread over (t, lg, r)
  const float bo3v = bo3[0];
  #pragma unroll
  for (int rt = 0; rt < 2; ++rt) {
    float sm = 0.f, sq = 0.f;
    #pragma unroll
    for (int t = 0; t < 8; ++t)
      #pragma unroll
      for (int r = 0; r < 4; ++r) { const float v = acc2[rt][t][r]; sm += v; sq = fmaf(v, v, sq); }
    sm += __shfl_xor(sm, 16, 64); sm += __shfl_xor(sm, 32, 64);
    sq += __shfl_xor(sq, 16, 64); sq += __shfl_xor(sq, 32, 64);
    const float mu = sm * (1.f / 128.f);
    const float rr = rsqrtf(sq * (1.f / 128.f) - mu * mu + 1e-5f);
    float acy = 0.f;
    #pragma unroll
    for (int t = 0; t < 8; ++t) {
      const f32x4 gv = *reinterpret_cast<const f32x4*>(g2 + t * 16 + lg * 4);
      const f32x4 bev = *reinterpret_cast<const f32x4*>(be2 + t * 16 + lg * 4);
      const f32x4 wv = *reinterpret_cast<const f32x4*>(Wo3 + t * 16 + lg * 4);
      #pragma unroll
      for (int r = 0; r < 4; ++r) {
        float v = (acc2[rt][t][r] - mu) * rr * gv[r] + bev[r];
        v = v > 0.f ? v : 0.01f * v;
        acy = fmaf(v, wv[r], acy);
      }
    }
    acy += __shfl_xor(acy, 16, 64); acy += __shfl_xor(acy, 32, 64);
    if (lg == 0) out[row0 + rt * 16 + lr] = acy + bo3v;
  }
}

extern "C" void kernel_launch(void* const* d_in, const int* in_sizes, int n_in,
                              void* d_out, int out_size, void* d_ws, size_t ws_size,
                              hipStream_t stream) {
  const float* obs  = (const float*)d_in[0];
  const float* actn = (const float*)d_in[1];
  const int*   adj  = (const int*)d_in[2];
  const float* W1   = (const float*)d_in[3];
  const float* a1s  = (const float*)d_in[4];
  const float* a1d  = (const float*)d_in[5];
  const float* b1   = (const float*)d_in[6];
  const float* W2   = (const float*)d_in[7];
  const float* a2s  = (const float*)d_in[8];
  const float* a2d  = (const float*)d_in[9];
  const float* b2   = (const float*)d_in[10];
  const float* Wo1  = (const float*)d_in[11];
  const float* bo1  = (const float*)d_in[12];
  const float* g1   = (const float*)d_in[13];
  const float* be1  = (const float*)d_in[14];
  const float* Wo2  = (const float*)d_in[15];
  const float* bo2  = (const float*)d_in[16];
  const float* g2   = (const float*)d_in[17];
  const float* be2  = (const float*)d_in[18];
  const float* Wo3  = (const float*)d_in[19];
  const float* bo3  = (const float*)d_in[20];

  uint16_t* hws = (uint16_t*)d_ws;                               // h: [B,192] bf16 = 100,663,296 B
  uint16_t* W1f = (uint16_t*)((char*)d_ws + 100663296);          // 98,304 B
  uint16_t* W2f = (uint16_t*)((char*)d_ws + 100663296 + 98304);  // 65,536 B
  float* outp = (float*)d_out;

  prep_kernel<<<192, 256, 0, stream>>>(Wo1, Wo2, W1f, W2f);
  gat_kernel<<<2048, 256, 0, stream>>>(obs, actn, adj, W1, a1s, a1d, b1,
                                       W2, a2s, a2d, b2, hws);
  mlp_kernel<<<4096, 128, 0, stream>>>(hws, W1f, W2f, bo1, g1, be1,
                                       bo2, g2, be2, Wo3, bo3, outp);
}

// Round 4
// 257.779 us; speedup vs baseline: 10.2744x; 3.5925x over previous
//
#include <hip/hip_runtime.h>
#include <hip/hip_bf16.h>
#include <stdint.h>

#define B_TOT 262144

typedef __attribute__((ext_vector_type(8))) short bf8;
typedef __attribute__((ext_vector_type(16))) float f32x16;

__device__ __forceinline__ float bf2f(uint32_t u)   { return __uint_as_float(u << 16); }
__device__ __forceinline__ float bfhi2f(uint32_t u) { return __uint_as_float(u & 0xffff0000u); }
__device__ __forceinline__ uint32_t f2bf(float x) {
  uint32_t u = __float_as_uint(x);
  return (u + 0x7fffu + ((u >> 16) & 1u)) >> 16;   // RTN-even
}
__device__ __forceinline__ uint32_t pkbf(float lo, float hi) {
  union { __hip_bfloat162 b; uint32_t u; } c;
  c.b = __float22bfloat162_rn(make_float2(lo, hi));
  return c.u;
}
__device__ __forceinline__ bf8 mkfrag(uint32_t w0, uint32_t w1, uint32_t w2, uint32_t w3) {
  union { uint32_t u[4]; bf8 v; } c;
  c.u[0] = w0; c.u[1] = w1; c.u[2] = w2; c.u[3] = w3;
  return c.v;
}

// ---------------- prep: pack adj counts + all weights into 32x32x16 A-frag order ----
// TRUE A/B frag k-mapping for mfma_32x32x16: lane l, elem e (0..7):
//   k = 8*(e>>2) + 4*(l>>5) + (e&3); row/col = l&31.  Buffer: [frag][l][e]
__global__ __launch_bounds__(256) void prep_kernel(
    const int* __restrict__ adj,
    const float* __restrict__ W1, const float* __restrict__ a1s, const float* __restrict__ a1d,
    const float* __restrict__ W2, const float* __restrict__ a2s, const float* __restrict__ a2d,
    const float* __restrict__ Wo1, const float* __restrict__ Wo2,
    uint32_t* __restrict__ cntp, uint16_t* __restrict__ W1F, uint16_t* __restrict__ W2F,
    uint16_t* __restrict__ Wo1F, uint16_t* __restrict__ Wo2F)
{
  const int gid = blockIdx.x * 256 + threadIdx.x;
  if (gid < B_TOT) {
    uint32_t cpv = 0;
    const int* ap = adj + (size_t)gid * 9;
    #pragma unroll
    for (int i = 0; i < 3; ++i)
      #pragma unroll
      for (int j = 0; j < 3; ++j) {
        uint32_t c = (uint32_t)ap[j * 3 + i] + (i == j ? 1u : 0u);  // adj^T + I
        cpv |= c << (2 * (3 * i + j));
      }
    cntp[gid] = cpv;
  }
  const int e = gid & 7, li = (gid >> 3) & 63;
  const int kfrag = 8 * (e >> 2) + 4 * (li >> 5) + (e & 3);   // TRUE mapping
  if (gid < 4608) {   // W1ext^T frags: [ks3][t3], rows 0..63=W1 cols, 64=W1@a1s, 65=W1@a1d
    const int rr = gid >> 9, t = rr % 3, ks = rr / 3;
    const int k = ks * 16 + kfrag, row = t * 32 + (li & 31);
    float v = 0.f;
    if (k < 35) {
      if (row < 64) v = W1[k * 64 + row];
      else if (row == 64) { float s = 0; for (int d = 0; d < 64; ++d) s += W1[k * 64 + d] * a1s[d]; v = s; }
      else if (row == 65) { float s = 0; for (int d = 0; d < 64; ++d) s += W1[k * 64 + d] * a1d[d]; v = s; }
    }
    W1F[gid] = (uint16_t)f2bf(v);
  }
  if (gid < 6144) {   // W2ext^T frags: [ks4][t3]
    const int rr = gid >> 9, t = rr % 3, ks = rr / 3;
    const int k = ks * 16 + kfrag, row = t * 32 + (li & 31);
    float v = 0.f;
    if (row < 64) v = W2[k * 64 + row];
    else if (row == 64) { float s = 0; for (int d = 0; d < 64; ++d) s += W2[k * 64 + d] * a2s[d]; v = s; }
    else if (row == 65) { float s = 0; for (int d = 0; d < 64; ++d) s += W2[k * 64 + d] * a2d[d]; v = s; }
    W2F[gid] = (uint16_t)f2bf(v);
  }
  if (gid < 49152) {  // Wo1^T frags: [ks12][t8]
    const int rr = gid >> 9, t = rr & 7, ks = rr >> 3;
    const int k = ks * 16 + kfrag, col = t * 32 + (li & 31);
    Wo1F[gid] = (uint16_t)f2bf(Wo1[k * 256 + col]);
  }
  if (gid < 32768) {  // Wo2^T frags: [ks16][t4]
    const int rr = gid >> 9, t = rr & 3, ks = rr >> 2;
    const int k = ks * 16 + kfrag, col = t * 32 + (li & 31);
    Wo2F[gid] = (uint16_t)f2bf(Wo2[k * 128 + col]);
  }
}

// ---------------- attention: scores from tile t=2 rows 64/65, per-lane softmax, agg ----
// Packs result pairwise in REG ORDER: Ph[i][t*8+p] = (reg 2p, reg 2p+1) of tile t.
// Because C-row formula == B-frag k formula, words [4ks..4ks+3] ARE the B-frag of k-tile ks.
template<bool DO_ELU>
__device__ __forceinline__ void attention(const f32x16 (&az)[3][3], uint32_t cp, int l, int hi,
                                          const float* __restrict__ bvec, uint32_t (&Ph)[3][16])
{
  float ss[3], sd[3];
  #pragma unroll
  for (int n = 0; n < 3; ++n) {
    ss[n] = __shfl(az[n][2][0], l & 31);   // row 64 = s_src (lanes<32, reg0)
    sd[n] = __shfl(az[n][2][1], l & 31);   // row 65 = s_dst
  }
  float ev[3][3], al[3][3];
  #pragma unroll
  for (int i = 0; i < 3; ++i) {
    float mx = -1e30f;
    #pragma unroll
    for (int j = 0; j < 3; ++j) {
      float s = ss[j] + sd[i];
      s = fmaxf(s, 0.2f * s);              // leaky_relu 0.2
      ev[i][j] = s;
      int c = (cp >> (2 * (3 * i + j))) & 3;
      mx = fmaxf(mx, c ? s : -1e30f);
    }
    float sum = 0.f;
    #pragma unroll
    for (int j = 0; j < 3; ++j) {
      int c = (cp >> (2 * (3 * i + j))) & 3;
      float p = (float)c * __expf(ev[i][j] - mx);
      al[i][j] = p; sum += p;
    }
    float inv = 1.0f / sum;
    #pragma unroll
    for (int j = 0; j < 3; ++j) al[i][j] *= inv;
  }
  #pragma unroll
  for (int t = 0; t < 2; ++t) {
    float bv[16];
    #pragma unroll
    for (int rq = 0; rq < 4; ++rq) {
      float4 b4 = *reinterpret_cast<const float4*>(bvec + t * 32 + rq * 8 + hi * 4);
      bv[4 * rq + 0] = b4.x; bv[4 * rq + 1] = b4.y; bv[4 * rq + 2] = b4.z; bv[4 * rq + 3] = b4.w;
    }
    #pragma unroll
    for (int i = 0; i < 3; ++i) {
      float hv[16];
      #pragma unroll
      for (int r = 0; r < 16; ++r) {
        float v = bv[r];
        v = fmaf(al[i][0], az[0][t][r], v);
        v = fmaf(al[i][1], az[1][t][r], v);
        v = fmaf(al[i][2], az[2][t][r], v);
        if (DO_ELU) v = v > 0.f ? v : (__expf(v) - 1.f);
        hv[r] = v;
      }
      #pragma unroll
      for (int p = 0; p < 8; ++p) Ph[i][t * 8 + p] = pkbf(hv[2 * p], hv[2 * p + 1]);
    }
  }
}

// ---------------- fused GAT+MLP: one wave owns 32 batch elements, zero LDS ----------
__global__ __launch_bounds__(256, 2) void fused_kernel(
    const float* __restrict__ obs, const float* __restrict__ act,
    const uint32_t* __restrict__ cntp,
    const uint16_t* __restrict__ W1F, const uint16_t* __restrict__ W2F,
    const float* __restrict__ b1, const float* __restrict__ b2,
    const uint16_t* __restrict__ Wo1F, const float* __restrict__ bo1,
    const float* __restrict__ g1, const float* __restrict__ be1,
    const uint16_t* __restrict__ Wo2F, const float* __restrict__ bo2,
    const float* __restrict__ g2, const float* __restrict__ be2,
    const float* __restrict__ Wo3, const float* __restrict__ bo3,
    float* __restrict__ out)
{
  const int tid = threadIdx.x;
  const int l = tid & 63, hi = l >> 5, col = l & 31;
  const int wid = blockIdx.x * 4 + (tid >> 6);
  const int e = wid * 32 + col;
  const uint32_t cp = cntp[e];
  const float* obs_e = obs + (size_t)e * 90;
  const float* act_e = act + (size_t)e * 15;

  // ===== GAT layer 1: z1^T[96,32] = W1ext^T @ x^T (x split hi+lo bf16) =====
  f32x16 az[3][3];
  #pragma unroll
  for (int n = 0; n < 3; ++n)
    #pragma unroll
    for (int t = 0; t < 3; ++t)
      #pragma unroll
      for (int r = 0; r < 16; ++r) az[n][t][r] = 0.f;

  #pragma unroll
  for (int ks = 0; ks < 3; ++ks) {
    bf8 xh[3], xl[3];
    #pragma unroll
    for (int n = 0; n < 3; ++n) {
      const float* on = obs_e + n * 30;
      const float* an = act_e + n * 5;
      float xv[8];
      #pragma unroll
      for (int r2 = 0; r2 < 2; ++r2) {
        if (ks == 2 && r2 == 1) {            // k >= 40: all pad
          xv[4] = xv[5] = xv[6] = xv[7] = 0.f;
          continue;
        }
        const int kb = ks * 16 + r2 * 8 + hi * 4;   // TRUE mapping run base
        #pragma unroll
        for (int j = 0; j < 4; ++j) {
          const int k = kb + j;
          float v = 0.f;
          if (k < 30) v = on[k];
          else if (k < 35) v = an[k - 30];
          xv[r2 * 4 + j] = v;
        }
      }
      uint32_t hw[4], lw[4];
      #pragma unroll
      for (int p = 0; p < 4; ++p) {
        hw[p] = pkbf(xv[2 * p], xv[2 * p + 1]);
        float ra = xv[2 * p]     - bf2f(hw[p]);
        float rb = xv[2 * p + 1] - bfhi2f(hw[p]);
        lw[p] = (__float_as_uint(ra) >> 16) | (__float_as_uint(rb) & 0xffff0000u);
      }
      xh[n] = mkfrag(hw[0], hw[1], hw[2], hw[3]);
      xl[n] = mkfrag(lw[0], lw[1], lw[2], lw[3]);
    }
    #pragma unroll
    for (int t = 0; t < 3; ++t) {
      bf8 a = *reinterpret_cast<const bf8*>(W1F + (size_t)((ks * 3 + t) * 64 + l) * 8);
      #pragma unroll
      for (int n = 0; n < 3; ++n) {
        az[n][t] = __builtin_amdgcn_mfma_f32_32x32x16_bf16(a, xh[n], az[n][t], 0, 0, 0);
        az[n][t] = __builtin_amdgcn_mfma_f32_32x32x16_bf16(a, xl[n], az[n][t], 0, 0, 0);
      }
    }
  }

  uint32_t Ph1[3][16];
  attention<true>(az, cp, l, hi, b1, Ph1);   // ELU

  // ===== GAT layer 2: z2^T[96,32] = W2ext^T @ h1^T; B-frag = 4 consecutive words =====
  f32x16 a2[3][3];
  #pragma unroll
  for (int n = 0; n < 3; ++n)
    #pragma unroll
    for (int t = 0; t < 3; ++t)
      #pragma unroll
      for (int r = 0; r < 16; ++r) a2[n][t][r] = 0.f;

  #pragma unroll
  for (int ks = 0; ks < 4; ++ks) {
    #pragma unroll
    for (int t = 0; t < 3; ++t) {
      bf8 a = *reinterpret_cast<const bf8*>(W2F + (size_t)((ks * 3 + t) * 64 + l) * 8);
      #pragma unroll
      for (int n = 0; n < 3; ++n) {
        bf8 br_ = mkfrag(Ph1[n][4 * ks], Ph1[n][4 * ks + 1], Ph1[n][4 * ks + 2], Ph1[n][4 * ks + 3]);
        a2[n][t] = __builtin_amdgcn_mfma_f32_32x32x16_bf16(a, br_, a2[n][t], 0, 0, 0);
      }
    }
  }

  uint32_t Ph2[3][16];
  attention<false>(a2, cp, l, hi, b2, Ph2);

  // ===== MLP layer 1: y1^T[256,32] = Wo1^T @ h2^T =====
  f32x16 acc1[8];
  #pragma unroll
  for (int t = 0; t < 8; ++t)
    #pragma unroll
    for (int rq = 0; rq < 4; ++rq) {
      float4 b4 = *reinterpret_cast<const float4*>(bo1 + t * 32 + rq * 8 + hi * 4);
      acc1[t][4 * rq + 0] = b4.x; acc1[t][4 * rq + 1] = b4.y;
      acc1[t][4 * rq + 2] = b4.z; acc1[t][4 * rq + 3] = b4.w;
    }
  #pragma unroll
  for (int ks = 0; ks < 12; ++ks) {
    const int n = ks >> 2, q0 = 4 * (ks & 3);
    bf8 br_ = mkfrag(Ph2[n][q0], Ph2[n][q0 + 1], Ph2[n][q0 + 2], Ph2[n][q0 + 3]);
    #pragma unroll
    for (int t = 0; t < 8; ++t) {
      bf8 a = *reinterpret_cast<const bf8*>(Wo1F + (size_t)((ks * 8 + t) * 64 + l) * 8);
      acc1[t] = __builtin_amdgcn_mfma_f32_32x32x16_bf16(a, br_, acc1[t], 0, 0, 0);
    }
  }
  // LN(256) + lrelu(0.01) -> pack bf16 (reg order)
  float sm = 0.f, sq = 0.f;
  #pragma unroll
  for (int t = 0; t < 8; ++t)
    #pragma unroll
    for (int r = 0; r < 16; ++r) { float v = acc1[t][r]; sm += v; sq = fmaf(v, v, sq); }
  sm += __shfl_xor(sm, 32); sq += __shfl_xor(sq, 32);
  float mu = sm * (1.f / 256.f);
  float rr = rsqrtf(sq * (1.f / 256.f) - mu * mu + 1e-5f);
  uint32_t py[64];
  #pragma unroll
  for (int t = 0; t < 8; ++t) {
    float hv[16];
    #pragma unroll
    for (int rq = 0; rq < 4; ++rq) {
      float4 gg = *reinterpret_cast<const float4*>(g1 + t * 32 + rq * 8 + hi * 4);
      float4 bb = *reinterpret_cast<const float4*>(be1 + t * 32 + rq * 8 + hi * 4);
      float v;
      v = (acc1[t][4 * rq + 0] - mu) * rr * gg.x + bb.x; hv[4 * rq + 0] = fmaxf(v, 0.01f * v);
      v = (acc1[t][4 * rq + 1] - mu) * rr * gg.y + bb.y; hv[4 * rq + 1] = fmaxf(v, 0.01f * v);
      v = (acc1[t][4 * rq + 2] - mu) * rr * gg.z + bb.z; hv[4 * rq + 2] = fmaxf(v, 0.01f * v);
      v = (acc1[t][4 * rq + 3] - mu) * rr * gg.w + bb.w; hv[4 * rq + 3] = fmaxf(v, 0.01f * v);
    }
    #pragma unroll
    for (int p = 0; p < 8; ++p) py[t * 8 + p] = pkbf(hv[2 * p], hv[2 * p + 1]);
  }

  // ===== MLP layer 2: y2^T[128,32] = Wo2^T @ y1^T =====
  f32x16 acc2[4];
  #pragma unroll
  for (int t = 0; t < 4; ++t)
    #pragma unroll
    for (int rq = 0; rq < 4; ++rq) {
      float4 b4 = *reinterpret_cast<const float4*>(bo2 + t * 32 + rq * 8 + hi * 4);
      acc2[t][4 * rq + 0] = b4.x; acc2[t][4 * rq + 1] = b4.y;
      acc2[t][4 * rq + 2] = b4.z; acc2[t][4 * rq + 3] = b4.w;
    }
  #pragma unroll
  for (int ks = 0; ks < 16; ++ks) {
    bf8 br_ = mkfrag(py[4 * ks], py[4 * ks + 1], py[4 * ks + 2], py[4 * ks + 3]);
    #pragma unroll
    for (int t = 0; t < 4; ++t) {
      bf8 a = *reinterpret_cast<const bf8*>(Wo2F + (size_t)((ks * 4 + t) * 64 + l) * 8);
      acc2[t] = __builtin_amdgcn_mfma_f32_32x32x16_bf16(a, br_, acc2[t], 0, 0, 0);
    }
  }
  // LN(128) + lrelu + final dot with Wo3
  sm = 0.f; sq = 0.f;
  #pragma unroll
  for (int t = 0; t < 4; ++t)
    #pragma unroll
    for (int r = 0; r < 16; ++r) { float v = acc2[t][r]; sm += v; sq = fmaf(v, v, sq); }
  sm += __shfl_xor(sm, 32); sq += __shfl_xor(sq, 32);
  mu = sm * (1.f / 128.f);
  rr = rsqrtf(sq * (1.f / 128.f) - mu * mu + 1e-5f);
  float acy = 0.f;
  #pragma unroll
  for (int t = 0; t < 4; ++t)
    #pragma unroll
    for (int rq = 0; rq < 4; ++rq) {
      float4 gg = *reinterpret_cast<const float4*>(g2 + t * 32 + rq * 8 + hi * 4);
      float4 bb = *reinterpret_cast<const float4*>(be2 + t * 32 + rq * 8 + hi * 4);
      float4 ww = *reinterpret_cast<const float4*>(Wo3 + t * 32 + rq * 8 + hi * 4);
      float v;
      v = (acc2[t][4 * rq + 0] - mu) * rr * gg.x + bb.x; acy = fmaf(fmaxf(v, 0.01f * v), ww.x, acy);
      v = (acc2[t][4 * rq + 1] - mu) * rr * gg.y + bb.y; acy = fmaf(fmaxf(v, 0.01f * v), ww.y, acy);
      v = (acc2[t][4 * rq + 2] - mu) * rr * gg.z + bb.z; acy = fmaf(fmaxf(v, 0.01f * v), ww.z, acy);
      v = (acc2[t][4 * rq + 3] - mu) * rr * gg.w + bb.w; acy = fmaf(fmaxf(v, 0.01f * v), ww.w, acy);
    }
  acy += __shfl_xor(acy, 32);
  if (hi == 0) out[e] = acy + bo3[0];
}

extern "C" void kernel_launch(void* const* d_in, const int* in_sizes, int n_in,
                              void* d_out, int out_size, void* d_ws, size_t ws_size,
                              hipStream_t stream) {
  const float* obs  = (const float*)d_in[0];
  const float* actn = (const float*)d_in[1];
  const int*   adj  = (const int*)d_in[2];
  const float* W1   = (const float*)d_in[3];
  const float* a1s  = (const float*)d_in[4];
  const float* a1d  = (const float*)d_in[5];
  const float* b1   = (const float*)d_in[6];
  const float* W2   = (const float*)d_in[7];
  const float* a2s  = (const float*)d_in[8];
  const float* a2d  = (const float*)d_in[9];
  const float* b2   = (const float*)d_in[10];
  const float* Wo1  = (const float*)d_in[11];
  const float* bo1  = (const float*)d_in[12];
  const float* g1   = (const float*)d_in[13];
  const float* be1  = (const float*)d_in[14];
  const float* Wo2  = (const float*)d_in[15];
  const float* bo2  = (const float*)d_in[16];
  const float* g2   = (const float*)d_in[17];
  const float* be2  = (const float*)d_in[18];
  const float* Wo3  = (const float*)d_in[19];
  const float* bo3  = (const float*)d_in[20];

  uint32_t* cntp = (uint32_t*)d_ws;                              // 1 MB
  uint16_t* W1F  = (uint16_t*)((char*)d_ws + (1 << 20));         // 4608 u16
  uint16_t* W2F  = W1F + 4608;                                   // 6144 u16
  uint16_t* Wo1F = W2F + 6144;                                   // 49152 u16
  uint16_t* Wo2F = Wo1F + 49152;                                 // 32768 u16
  float* outp = (float*)d_out;

  prep_kernel<<<1024, 256, 0, stream>>>(adj, W1, a1s, a1d, W2, a2s, a2d, Wo1, Wo2,
                                        cntp, W1F, W2F, Wo1F, Wo2F);
  fused_kernel<<<2048, 256, 0, stream>>>(obs, actn, cntp, W1F, W2F, b1, b2,
                                         Wo1F, bo1, g1, be1, Wo2F, bo2, g2, be2,
                                         Wo3, bo3, outp);
}

// Round 5
// 162.006 us; speedup vs baseline: 16.3483x; 1.5912x over previous
//
#include <hip/hip_runtime.h>
#include <hip/hip_bf16.h>
#include <stdint.h>

#define B_TOT 262144

typedef __attribute__((ext_vector_type(8))) short bf8;
typedef __attribute__((ext_vector_type(16))) float f32x16;

__device__ __forceinline__ float bf2f(uint32_t u)   { return __uint_as_float(u << 16); }
__device__ __forceinline__ float bfhi2f(uint32_t u) { return __uint_as_float(u & 0xffff0000u); }
__device__ __forceinline__ uint32_t f2bf(float x) {
  uint32_t u = __float_as_uint(x);
  return (u + 0x7fffu + ((u >> 16) & 1u)) >> 16;   // RTN-even
}
__device__ __forceinline__ uint32_t pkbf(float lo, float hi) {
  union { __hip_bfloat162 b; uint32_t u; } c;
  c.b = __float22bfloat162_rn(make_float2(lo, hi));
  return c.u;
}
__device__ __forceinline__ bf8 mkfrag(uint32_t w0, uint32_t w1, uint32_t w2, uint32_t w3) {
  union { uint32_t u[4]; bf8 v; } c;
  c.u[0] = w0; c.u[1] = w1; c.u[2] = w2; c.u[3] = w3;
  return c.v;
}

// ---------------- prep: adj counts, W frags (true k-map), W@a score vectors ----------
// A/B frag k-mapping for mfma_32x32x16: lane l, elem e: k = 8*(e>>2)+4*(l>>5)+(e&3).
__global__ __launch_bounds__(256) void prep_kernel(
    const int* __restrict__ adj,
    const float* __restrict__ W1, const float* __restrict__ a1s, const float* __restrict__ a1d,
    const float* __restrict__ W2, const float* __restrict__ a2s, const float* __restrict__ a2d,
    const float* __restrict__ Wo1, const float* __restrict__ Wo2,
    uint32_t* __restrict__ cntp, uint16_t* __restrict__ W1F, uint16_t* __restrict__ W2F,
    uint16_t* __restrict__ Wo1F, uint16_t* __restrict__ Wo2F, float* __restrict__ wvec)
{
  const int gid = blockIdx.x * 256 + threadIdx.x;
  if (gid < B_TOT) {
    uint32_t cpv = 0;
    const int* ap = adj + (size_t)gid * 9;
    #pragma unroll
    for (int i = 0; i < 3; ++i)
      #pragma unroll
      for (int j = 0; j < 3; ++j) {
        uint32_t c = (uint32_t)ap[j * 3 + i] + (i == j ? 1u : 0u);  // adj^T + I
        cpv |= c << (2 * (3 * i + j));
      }
    cntp[gid] = cpv;
  }
  const int e = gid & 7, li = (gid >> 3) & 63;
  const int kfrag = 8 * (e >> 2) + 4 * (li >> 5) + (e & 3);
  if (gid < 3072) {   // W1^T frags [ks3][t2]
    const int f = gid >> 9, t = f & 1, ks = f >> 1;
    const int k = ks * 16 + kfrag, row = t * 32 + (li & 31);
    W1F[gid] = (uint16_t)f2bf(k < 35 ? W1[k * 64 + row] : 0.f);
  }
  if (gid < 4096) {   // W2^T frags [ks4][t2]
    const int f = gid >> 9, t = f & 1, ks = f >> 1;
    const int k = ks * 16 + kfrag, row = t * 32 + (li & 31);
    W2F[gid] = (uint16_t)f2bf(W2[k * 64 + row]);
  }
  if (gid < 49152) {  // Wo1^T frags [ks12][t8]
    const int rr = gid >> 9, t = rr & 7, ks = rr >> 3;
    const int k = ks * 16 + kfrag, col = t * 32 + (li & 31);
    Wo1F[gid] = (uint16_t)f2bf(Wo1[k * 256 + col]);
  }
  if (gid < 32768) {  // Wo2^T frags [ks16][t4]
    const int rr = gid >> 9, t = rr & 3, ks = rr >> 2;
    const int k = ks * 16 + kfrag, col = t * 32 + (li & 31);
    Wo2F[gid] = (uint16_t)f2bf(Wo2[k * 128 + col]);
  }
  if (gid < 224) {    // score vectors: [0..63]=W1@a1s (pad), [64..127]=W1@a1d, [128..191]=W2@a2s, [192..255]=W2@a2d
    if (gid < 48) {
      float s = 0.f; if (gid < 35) for (int d = 0; d < 64; ++d) s += W1[gid * 64 + d] * a1s[d];
      wvec[gid] = s;
    } else if (gid < 96) {
      const int k = gid - 48; float s = 0.f;
      if (k < 35) for (int d = 0; d < 64; ++d) s += W1[k * 64 + d] * a1d[d];
      wvec[64 + k] = s;
    } else if (gid < 160) {
      const int k = gid - 96; float s = 0.f;
      for (int d = 0; d < 64; ++d) s += W2[k * 64 + d] * a2s[d];
      wvec[128 + k] = s;
    } else {
      const int k = gid - 160; float s = 0.f;
      for (int d = 0; d < 64; ++d) s += W2[k * 64 + d] * a2d[d];
      wvec[192 + k] = s;
    }
  }
}

// ---------------- attention: given reduced ss/sd, softmax + aggregate (+ next scores) --
template<bool DO_ELU, bool NS>
__device__ __forceinline__ void attention(const f32x16 (&az)[3][2],
    const float (&ss)[3], const float (&sd)[3], uint32_t cp, int hi,
    const float* __restrict__ bvec, const float* __restrict__ nxs, const float* __restrict__ nxd,
    uint32_t (&Ph)[3][16], float (&ss2)[3], float (&sd2)[3])
{
  float al[3][3];
  #pragma unroll
  for (int i = 0; i < 3; ++i) {
    float ev[3]; float mx = -1e30f;
    #pragma unroll
    for (int j = 0; j < 3; ++j) {
      float s = ss[j] + sd[i];
      s = fmaxf(s, 0.2f * s);              // leaky_relu 0.2
      ev[j] = s;
      int c = (cp >> (2 * (3 * i + j))) & 3;
      mx = fmaxf(mx, c ? s : -1e30f);
    }
    float sum = 0.f;
    #pragma unroll
    for (int j = 0; j < 3; ++j) {
      int c = (cp >> (2 * (3 * i + j))) & 3;
      float p = (float)c * __expf(ev[j] - mx);
      al[i][j] = p; sum += p;
    }
    float inv = 1.0f / sum;
    #pragma unroll
    for (int j = 0; j < 3; ++j) al[i][j] *= inv;
  }
  #pragma unroll
  for (int t = 0; t < 2; ++t) {
    float bv[16], nsv[16], ndv[16];
    #pragma unroll
    for (int rq = 0; rq < 4; ++rq) {
      float4 b4 = *reinterpret_cast<const float4*>(bvec + t * 32 + rq * 8 + hi * 4);
      bv[4 * rq + 0] = b4.x; bv[4 * rq + 1] = b4.y; bv[4 * rq + 2] = b4.z; bv[4 * rq + 3] = b4.w;
      if (NS) {
        float4 s4 = *reinterpret_cast<const float4*>(nxs + t * 32 + rq * 8 + hi * 4);
        float4 d4 = *reinterpret_cast<const float4*>(nxd + t * 32 + rq * 8 + hi * 4);
        nsv[4 * rq + 0] = s4.x; nsv[4 * rq + 1] = s4.y; nsv[4 * rq + 2] = s4.z; nsv[4 * rq + 3] = s4.w;
        ndv[4 * rq + 0] = d4.x; ndv[4 * rq + 1] = d4.y; ndv[4 * rq + 2] = d4.z; ndv[4 * rq + 3] = d4.w;
      }
    }
    #pragma unroll
    for (int i = 0; i < 3; ++i) {
      float hv[16];
      #pragma unroll
      for (int r = 0; r < 16; ++r) {
        float v = bv[r];
        v = fmaf(al[i][0], az[0][t][r], v);
        v = fmaf(al[i][1], az[1][t][r], v);
        v = fmaf(al[i][2], az[2][t][r], v);
        if (DO_ELU) v = v > 0.f ? v : (__expf(v) - 1.f);
        if (NS) { ss2[i] = fmaf(v, nsv[r], ss2[i]); sd2[i] = fmaf(v, ndv[r], sd2[i]); }
        hv[r] = v;
      }
      #pragma unroll
      for (int p = 0; p < 8; ++p) Ph[i][t * 8 + p] = pkbf(hv[2 * p], hv[2 * p + 1]);
    }
  }
}

// ---------------- fused GAT+MLP: 32 elements/wave, weights LDS-staged -----------------
__global__ __launch_bounds__(256, 3) void fused_kernel(
    const float* __restrict__ obs, const float* __restrict__ act,
    const uint32_t* __restrict__ cntp,
    const uint16_t* __restrict__ W1F, const uint16_t* __restrict__ W2F,
    const float* __restrict__ b1, const float* __restrict__ b2,
    const uint16_t* __restrict__ Wo1F, const float* __restrict__ bo1,
    const float* __restrict__ g1, const float* __restrict__ be1,
    const uint16_t* __restrict__ Wo2F, const float* __restrict__ bo2,
    const float* __restrict__ g2, const float* __restrict__ be2,
    const float* __restrict__ Wo3, const float* __restrict__ bo3,
    const float* __restrict__ wvec, float* __restrict__ out)
{
  __shared__ __align__(16) uint16_t W1s[3072];
  __shared__ __align__(16) uint16_t W2s[4096];
  __shared__ __align__(16) uint16_t Wo2s[32768];
  const int tid = threadIdx.x;
  {
    uint4* d1 = (uint4*)W1s;  const uint4* s1 = (const uint4*)W1F;
    for (int i = tid; i < 384; i += 256) d1[i] = s1[i];
    uint4* d2 = (uint4*)W2s;  const uint4* s2 = (const uint4*)W2F;
    for (int i = tid; i < 512; i += 256) d2[i] = s2[i];
    uint4* d3 = (uint4*)Wo2s; const uint4* s3 = (const uint4*)Wo2F;
    for (int i = tid; i < 4096; i += 256) d3[i] = s3[i];
  }
  __syncthreads();

  const int l = tid & 63, hi = l >> 5, col = l & 31;
  const int wid = blockIdx.x * 4 + (tid >> 6);
  const int e = wid * 32 + col;
  const uint32_t cp = cntp[e];
  const float* obs_e = obs + (size_t)e * 90;
  const float* act_e = act + (size_t)e * 15;

  // ===== GAT layer 1 (+ per-lane score dots in f32) =====
  f32x16 az[3][2];
  #pragma unroll
  for (int n = 0; n < 3; ++n)
    #pragma unroll
    for (int t = 0; t < 2; ++t)
      #pragma unroll
      for (int r = 0; r < 16; ++r) az[n][t][r] = 0.f;
  float ss1[3] = {0, 0, 0}, sd1[3] = {0, 0, 0};

  #pragma unroll
  for (int ks = 0; ks < 3; ++ks) {
    bf8 xh[3], xl[3];
    #pragma unroll
    for (int n = 0; n < 3; ++n) {
      const float* on = obs_e + n * 30;
      const float* an = act_e + n * 15 - 30;     // an[k] valid for k>=30 via (k-30)+n*... see below
      float xv[8];
      #pragma unroll
      for (int r2 = 0; r2 < 2; ++r2) {
        if (ks == 2 && r2 == 1) { xv[4] = xv[5] = xv[6] = xv[7] = 0.f; continue; }
        const int kb = ks * 16 + r2 * 8 + hi * 4;
        #pragma unroll
        for (int j = 0; j < 4; ++j) {
          const int k = kb + j;
          float v = 0.f;
          if (k < 30) v = on[k];
          else if (k < 35) v = act_e[n * 5 + k - 30];
          xv[r2 * 4 + j] = v;
        }
        // score dot vs W1@a vectors (f32)
        float4 s4 = *reinterpret_cast<const float4*>(wvec + kb);
        float4 d4 = *reinterpret_cast<const float4*>(wvec + 64 + kb);
        ss1[n] = fmaf(xv[r2 * 4 + 0], s4.x, ss1[n]); sd1[n] = fmaf(xv[r2 * 4 + 0], d4.x, sd1[n]);
        ss1[n] = fmaf(xv[r2 * 4 + 1], s4.y, ss1[n]); sd1[n] = fmaf(xv[r2 * 4 + 1], d4.y, sd1[n]);
        ss1[n] = fmaf(xv[r2 * 4 + 2], s4.z, ss1[n]); sd1[n] = fmaf(xv[r2 * 4 + 2], d4.z, sd1[n]);
        ss1[n] = fmaf(xv[r2 * 4 + 3], s4.w, ss1[n]); sd1[n] = fmaf(xv[r2 * 4 + 3], d4.w, sd1[n]);
      }
      uint32_t hw[4], lw[4];
      #pragma unroll
      for (int p = 0; p < 4; ++p) {
        hw[p] = pkbf(xv[2 * p], xv[2 * p + 1]);
        float ra = xv[2 * p]     - bf2f(hw[p]);
        float rb = xv[2 * p + 1] - bfhi2f(hw[p]);
        lw[p] = (__float_as_uint(ra) >> 16) | (__float_as_uint(rb) & 0xffff0000u);
      }
      xh[n] = mkfrag(hw[0], hw[1], hw[2], hw[3]);
      xl[n] = mkfrag(lw[0], lw[1], lw[2], lw[3]);
    }
    #pragma unroll
    for (int t = 0; t < 2; ++t) {
      bf8 a = *reinterpret_cast<const bf8*>(&W1s[(ks * 2 + t) * 512 + l * 8]);
      #pragma unroll
      for (int n = 0; n < 3; ++n) {
        az[n][t] = __builtin_amdgcn_mfma_f32_32x32x16_bf16(a, xh[n], az[n][t], 0, 0, 0);
        az[n][t] = __builtin_amdgcn_mfma_f32_32x32x16_bf16(a, xl[n], az[n][t], 0, 0, 0);
      }
    }
  }
  #pragma unroll
  for (int n = 0; n < 3; ++n) {
    ss1[n] += __shfl_xor(ss1[n], 32);
    sd1[n] += __shfl_xor(sd1[n], 32);
  }

  uint32_t Ph1[3][16];
  float ss2[3] = {0, 0, 0}, sd2[3] = {0, 0, 0};
  attention<true, true>(az, ss1, sd1, cp, hi, b1, wvec + 128, wvec + 192, Ph1, ss2, sd2);
  #pragma unroll
  for (int n = 0; n < 3; ++n) {
    ss2[n] += __shfl_xor(ss2[n], 32);
    sd2[n] += __shfl_xor(sd2[n], 32);
  }

  // ===== GAT layer 2 =====
  f32x16 a2[3][2];
  #pragma unroll
  for (int n = 0; n < 3; ++n)
    #pragma unroll
    for (int t = 0; t < 2; ++t)
      #pragma unroll
      for (int r = 0; r < 16; ++r) a2[n][t][r] = 0.f;
  #pragma unroll
  for (int ks = 0; ks < 4; ++ks) {
    #pragma unroll
    for (int t = 0; t < 2; ++t) {
      bf8 a = *reinterpret_cast<const bf8*>(&W2s[(ks * 2 + t) * 512 + l * 8]);
      #pragma unroll
      for (int n = 0; n < 3; ++n) {
        bf8 br_ = mkfrag(Ph1[n][4 * ks], Ph1[n][4 * ks + 1], Ph1[n][4 * ks + 2], Ph1[n][4 * ks + 3]);
        a2[n][t] = __builtin_amdgcn_mfma_f32_32x32x16_bf16(a, br_, a2[n][t], 0, 0, 0);
      }
    }
  }

  uint32_t Ph2[3][16];
  float du1[3], du2[3];
  attention<false, false>(a2, ss2, sd2, cp, hi, b2, nullptr, nullptr, Ph2, du1, du2);

  __syncthreads();   // align block's waves so the Wo1F stream reuses L1

  // ===== MLP layer 1: two halves of 128 features; pre-LN bf16 pack =====
  float sm = 0.f, sq = 0.f;
  uint32_t y[64];
  #pragma unroll
  for (int half = 0; half < 2; ++half) {
    f32x16 acc[4];
    #pragma unroll
    for (int t = 0; t < 4; ++t)
      #pragma unroll
      for (int rq = 0; rq < 4; ++rq) {
        float4 b4 = *reinterpret_cast<const float4*>(bo1 + (half * 4 + t) * 32 + rq * 8 + hi * 4);
        acc[t][4 * rq + 0] = b4.x; acc[t][4 * rq + 1] = b4.y;
        acc[t][4 * rq + 2] = b4.z; acc[t][4 * rq + 3] = b4.w;
      }
    #pragma unroll
    for (int ks = 0; ks < 12; ++ks) {
      const int n = ks >> 2, q0 = 4 * (ks & 3);
      bf8 br_ = mkfrag(Ph2[n][q0], Ph2[n][q0 + 1], Ph2[n][q0 + 2], Ph2[n][q0 + 3]);
      #pragma unroll
      for (int t = 0; t < 4; ++t) {
        bf8 a = *reinterpret_cast<const bf8*>(Wo1F + (size_t)((ks * 8 + half * 4 + t) * 64 + l) * 8);
        acc[t] = __builtin_amdgcn_mfma_f32_32x32x16_bf16(a, br_, acc[t], 0, 0, 0);
      }
    }
    #pragma unroll
    for (int t = 0; t < 4; ++t) {
      #pragma unroll
      for (int r = 0; r < 16; ++r) { const float v = acc[t][r]; sm += v; sq = fmaf(v, v, sq); }
      #pragma unroll
      for (int p = 0; p < 8; ++p)
        y[(half * 4 + t) * 8 + p] = pkbf(acc[t][2 * p], acc[t][2 * p + 1]);
    }
  }
  sm += __shfl_xor(sm, 32); sq += __shfl_xor(sq, 32);
  float mu = sm * (1.f / 256.f);
  float rr = rsqrtf(sq * (1.f / 256.f) - mu * mu + 1e-5f);
  #pragma unroll
  for (int tg = 0; tg < 8; ++tg)
    #pragma unroll
    for (int rq = 0; rq < 4; ++rq) {
      float4 gg = *reinterpret_cast<const float4*>(g1 + tg * 32 + rq * 8 + hi * 4);
      float4 bb = *reinterpret_cast<const float4*>(be1 + tg * 32 + rq * 8 + hi * 4);
      const int w0 = tg * 8 + rq * 2;
      float v0 = (bf2f(y[w0]) - mu) * rr * gg.x + bb.x;        v0 = fmaxf(v0, 0.01f * v0);
      float v1 = (bfhi2f(y[w0]) - mu) * rr * gg.y + bb.y;      v1 = fmaxf(v1, 0.01f * v1);
      y[w0] = pkbf(v0, v1);
      float v2 = (bf2f(y[w0 + 1]) - mu) * rr * gg.z + bb.z;    v2 = fmaxf(v2, 0.01f * v2);
      float v3 = (bfhi2f(y[w0 + 1]) - mu) * rr * gg.w + bb.w;  v3 = fmaxf(v3, 0.01f * v3);
      y[w0 + 1] = pkbf(v2, v3);
    }

  // ===== MLP layer 2 (Wo2 from LDS) =====
  f32x16 acc2[4];
  #pragma unroll
  for (int t = 0; t < 4; ++t)
    #pragma unroll
    for (int rq = 0; rq < 4; ++rq) {
      float4 b4 = *reinterpret_cast<const float4*>(bo2 + t * 32 + rq * 8 + hi * 4);
      acc2[t][4 * rq + 0] = b4.x; acc2[t][4 * rq + 1] = b4.y;
      acc2[t][4 * rq + 2] = b4.z; acc2[t][4 * rq + 3] = b4.w;
    }
  #pragma unroll
  for (int ks = 0; ks < 16; ++ks) {
    bf8 br_ = mkfrag(y[4 * ks], y[4 * ks + 1], y[4 * ks + 2], y[4 * ks + 3]);
    #pragma unroll
    for (int t = 0; t < 4; ++t) {
      bf8 a = *reinterpret_cast<const bf8*>(&Wo2s[(ks * 4 + t) * 512 + l * 8]);
      acc2[t] = __builtin_amdgcn_mfma_f32_32x32x16_bf16(a, br_, acc2[t], 0, 0, 0);
    }
  }
  // LN(128) + lrelu + final dot with Wo3
  sm = 0.f; sq = 0.f;
  #pragma unroll
  for (int t = 0; t < 4; ++t)
    #pragma unroll
    for (int r = 0; r < 16; ++r) { const float v = acc2[t][r]; sm += v; sq = fmaf(v, v, sq); }
  sm += __shfl_xor(sm, 32); sq += __shfl_xor(sq, 32);
  mu = sm * (1.f / 128.f);
  rr = rsqrtf(sq * (1.f / 128.f) - mu * mu + 1e-5f);
  float acy = 0.f;
  #pragma unroll
  for (int t = 0; t < 4; ++t)
    #pragma unroll
    for (int rq = 0; rq < 4; ++rq) {
      float4 gg = *reinterpret_cast<const float4*>(g2 + t * 32 + rq * 8 + hi * 4);
      float4 bb = *reinterpret_cast<const float4*>(be2 + t * 32 + rq * 8 + hi * 4);
      float4 ww = *reinterpret_cast<const float4*>(Wo3 + t * 32 + rq * 8 + hi * 4);
      float v;
      v = (acc2[t][4 * rq + 0] - mu) * rr * gg.x + bb.x; acy = fmaf(fmaxf(v, 0.01f * v), ww.x, acy);
      v = (acc2[t][4 * rq + 1] - mu) * rr * gg.y + bb.y; acy = fmaf(fmaxf(v, 0.01f * v), ww.y, acy);
      v = (acc2[t][4 * rq + 2] - mu) * rr * gg.z + bb.z; acy = fmaf(fmaxf(v, 0.01f * v), ww.z, acy);
      v = (acc2[t][4 * rq + 3] - mu) * rr * gg.w + bb.w; acy = fmaf(fmaxf(v, 0.01f * v), ww.w, acy);
    }
  acy += __shfl_xor(acy, 32);
  if (hi == 0) out[e] = acy + bo3[0];
}

extern "C" void kernel_launch(void* const* d_in, const int* in_sizes, int n_in,
                              void* d_out, int out_size, void* d_ws, size_t ws_size,
                              hipStream_t stream) {
  const float* obs  = (const float*)d_in[0];
  const float* actn = (const float*)d_in[1];
  const int*   adj  = (const int*)d_in[2];
  const float* W1   = (const float*)d_in[3];
  const float* a1s  = (const float*)d_in[4];
  const float* a1d  = (const float*)d_in[5];
  const float* b1   = (const float*)d_in[6];
  const float* W2   = (const float*)d_in[7];
  const float* a2s  = (const float*)d_in[8];
  const float* a2d  = (const float*)d_in[9];
  const float* b2   = (const float*)d_in[10];
  const float* Wo1  = (const float*)d_in[11];
  const float* bo1  = (const float*)d_in[12];
  const float* g1   = (const float*)d_in[13];
  const float* be1  = (const float*)d_in[14];
  const float* Wo2  = (const float*)d_in[15];
  const float* bo2  = (const float*)d_in[16];
  const float* g2   = (const float*)d_in[17];
  const float* be2  = (const float*)d_in[18];
  const float* Wo3  = (const float*)d_in[19];
  const float* bo3  = (const float*)d_in[20];

  char* ws = (char*)d_ws;
  uint32_t* cntp = (uint32_t*)ws;                       // 1 MB
  uint16_t* W1F  = (uint16_t*)(ws + 1048576);           // 6144 B
  uint16_t* W2F  = (uint16_t*)(ws + 1048576 + 8192);    // 8192 B
  uint16_t* Wo1F = (uint16_t*)(ws + 1048576 + 16384);   // 98304 B
  uint16_t* Wo2F = (uint16_t*)(ws + 1048576 + 114688);  // 65536 B
  float*    wvec = (float*)(ws + 1048576 + 180224);     // 1024 B
  float* outp = (float*)d_out;

  prep_kernel<<<1024, 256, 0, stream>>>(adj, W1, a1s, a1d, W2, a2s, a2d, Wo1, Wo2,
                                        cntp, W1F, W2F, Wo1F, Wo2F, wvec);
  fused_kernel<<<2048, 256, 0, stream>>>(obs, actn, cntp, W1F, W2F, b1, b2,
                                         Wo1F, bo1, g1, be1, Wo2F, bo2, g2, be2,
                                         Wo3, bo3, wvec, outp);
}

// Round 6
// 122.563 us; speedup vs baseline: 21.6094x; 1.3218x over previous
//
#include <hip/hip_runtime.h>
#include <hip/hip_bf16.h>
#include <stdint.h>

#define B_TOT 262144

typedef __attribute__((ext_vector_type(8))) short bf8;
typedef __attribute__((ext_vector_type(16))) float f32x16;

__device__ __forceinline__ float bf2f(uint32_t u)   { return __uint_as_float(u << 16); }
__device__ __forceinline__ float bfhi2f(uint32_t u) { return __uint_as_float(u & 0xffff0000u); }
__device__ __forceinline__ uint32_t f2bf(float x) {
  uint32_t u = __float_as_uint(x);
  return (u + 0x7fffu + ((u >> 16) & 1u)) >> 16;   // RTN-even
}
__device__ __forceinline__ uint32_t pkbf(float lo, float hi) {
  union { __hip_bfloat162 b; uint32_t u; } c;
  c.b = __float22bfloat162_rn(make_float2(lo, hi));
  return c.u;
}
__device__ __forceinline__ bf8 mkfrag(uint32_t w0, uint32_t w1, uint32_t w2, uint32_t w3) {
  union { uint32_t u[4]; bf8 v; } c;
  c.u[0] = w0; c.u[1] = w1; c.u[2] = w2; c.u[3] = w3;
  return c.v;
}

// ---------------- prep: adj counts, W frags (true k-map), W@a score vectors ----------
// A/B frag k-mapping for mfma_32x32x16: lane l, elem e: k = 8*(e>>2)+4*(l>>5)+(e&3).
__global__ __launch_bounds__(256) void prep_kernel(
    const int* __restrict__ adj,
    const float* __restrict__ W1, const float* __restrict__ a1s, const float* __restrict__ a1d,
    const float* __restrict__ W2, const float* __restrict__ a2s, const float* __restrict__ a2d,
    const float* __restrict__ Wo1, const float* __restrict__ Wo2,
    uint32_t* __restrict__ cntp, uint16_t* __restrict__ W1F, uint16_t* __restrict__ W2F,
    uint16_t* __restrict__ Wo1F, uint16_t* __restrict__ Wo2F, float* __restrict__ wvec)
{
  const int gid = blockIdx.x * 256 + threadIdx.x;
  if (gid < B_TOT) {
    uint32_t cpv = 0;
    const int* ap = adj + (size_t)gid * 9;
    #pragma unroll
    for (int i = 0; i < 3; ++i)
      #pragma unroll
      for (int j = 0; j < 3; ++j) {
        uint32_t c = (uint32_t)ap[j * 3 + i] + (i == j ? 1u : 0u);  // adj^T + I
        cpv |= c << (2 * (3 * i + j));
      }
    cntp[gid] = cpv;
  }
  const int e = gid & 7, li = (gid >> 3) & 63;
  const int kfrag = 8 * (e >> 2) + 4 * (li >> 5) + (e & 3);
  if (gid < 3072) {   // W1^T frags [ks3][t2]
    const int f = gid >> 9, t = f & 1, ks = f >> 1;
    const int k = ks * 16 + kfrag, row = t * 32 + (li & 31);
    W1F[gid] = (uint16_t)f2bf(k < 35 ? W1[k * 64 + row] : 0.f);
  }
  if (gid < 4096) {   // W2^T frags [ks4][t2]
    const int f = gid >> 9, t = f & 1, ks = f >> 1;
    const int k = ks * 16 + kfrag, row = t * 32 + (li & 31);
    W2F[gid] = (uint16_t)f2bf(W2[k * 64 + row]);
  }
  if (gid < 49152) {  // Wo1^T frags [ks12][t8]
    const int rr = gid >> 9, t = rr & 7, ks = rr >> 3;
    const int k = ks * 16 + kfrag, col = t * 32 + (li & 31);
    Wo1F[gid] = (uint16_t)f2bf(Wo1[k * 256 + col]);
  }
  if (gid < 32768) {  // Wo2^T frags [ks16][t4]
    const int rr = gid >> 9, t = rr & 3, ks = rr >> 2;
    const int k = ks * 16 + kfrag, col = t * 32 + (li & 31);
    Wo2F[gid] = (uint16_t)f2bf(Wo2[k * 128 + col]);
  }
  if (gid < 224) {    // score vectors: [0..63]=W1@a1s (pad), [64..127]=W1@a1d, [128..191]=W2@a2s, [192..255]=W2@a2d
    if (gid < 48) {
      float s = 0.f; if (gid < 35) for (int d = 0; d < 64; ++d) s += W1[gid * 64 + d] * a1s[d];
      wvec[gid] = s;
    } else if (gid < 96) {
      const int k = gid - 48; float s = 0.f;
      if (k < 35) for (int d = 0; d < 64; ++d) s += W1[k * 64 + d] * a1d[d];
      wvec[64 + k] = s;
    } else if (gid < 160) {
      const int k = gid - 96; float s = 0.f;
      for (int d = 0; d < 64; ++d) s += W2[k * 64 + d] * a2s[d];
      wvec[128 + k] = s;
    } else {
      const int k = gid - 160; float s = 0.f;
      for (int d = 0; d < 64; ++d) s += W2[k * 64 + d] * a2d[d];
      wvec[192 + k] = s;
    }
  }
}

// ---------------- attention: given reduced ss/sd, softmax + aggregate (+ next scores) --
template<bool DO_ELU, bool NS>
__device__ __forceinline__ void attention(const f32x16 (&az)[3][2],
    const float (&ss)[3], const float (&sd)[3], uint32_t cp, int hi,
    const float* __restrict__ bvec, const float* __restrict__ nxs, const float* __restrict__ nxd,
    uint32_t (&Ph)[3][16], float (&ss2)[3], float (&sd2)[3])
{
  float al[3][3];
  #pragma unroll
  for (int i = 0; i < 3; ++i) {
    float ev[3]; float mx = -1e30f;
    #pragma unroll
    for (int j = 0; j < 3; ++j) {
      float s = ss[j] + sd[i];
      s = fmaxf(s, 0.2f * s);              // leaky_relu 0.2
      ev[j] = s;
      int c = (cp >> (2 * (3 * i + j))) & 3;
      mx = fmaxf(mx, c ? s : -1e30f);
    }
    float sum = 0.f;
    #pragma unroll
    for (int j = 0; j < 3; ++j) {
      int c = (cp >> (2 * (3 * i + j))) & 3;
      float p = (float)c * __expf(ev[j] - mx);
      al[i][j] = p; sum += p;
    }
    float inv = 1.0f / sum;
    #pragma unroll
    for (int j = 0; j < 3; ++j) al[i][j] *= inv;
  }
  #pragma unroll
  for (int t = 0; t < 2; ++t) {
    float bv[16], nsv[16], ndv[16];
    #pragma unroll
    for (int rq = 0; rq < 4; ++rq) {
      float4 b4 = *reinterpret_cast<const float4*>(bvec + t * 32 + rq * 8 + hi * 4);
      bv[4 * rq + 0] = b4.x; bv[4 * rq + 1] = b4.y; bv[4 * rq + 2] = b4.z; bv[4 * rq + 3] = b4.w;
      if (NS) {
        float4 s4 = *reinterpret_cast<const float4*>(nxs + t * 32 + rq * 8 + hi * 4);
        float4 d4 = *reinterpret_cast<const float4*>(nxd + t * 32 + rq * 8 + hi * 4);
        nsv[4 * rq + 0] = s4.x; nsv[4 * rq + 1] = s4.y; nsv[4 * rq + 2] = s4.z; nsv[4 * rq + 3] = s4.w;
        ndv[4 * rq + 0] = d4.x; ndv[4 * rq + 1] = d4.y; ndv[4 * rq + 2] = d4.z; ndv[4 * rq + 3] = d4.w;
      }
    }
    #pragma unroll
    for (int i = 0; i < 3; ++i) {
      float hv[16];
      #pragma unroll
      for (int r = 0; r < 16; ++r) {
        float v = bv[r];
        v = fmaf(al[i][0], az[0][t][r], v);
        v = fmaf(al[i][1], az[1][t][r], v);
        v = fmaf(al[i][2], az[2][t][r], v);
        if (DO_ELU) v = v > 0.f ? v : (__expf(v) - 1.f);
        if (NS) { ss2[i] = fmaf(v, nsv[r], ss2[i]); sd2[i] = fmaf(v, ndv[r], sd2[i]); }
        hv[r] = v;
      }
      #pragma unroll
      for (int p = 0; p < 8; ++p) Ph[i][t * 8 + p] = pkbf(hv[2 * p], hv[2 * p + 1]);
    }
  }
}

// ---------------- fused GAT+MLP: 32 elements/wave; LDS = Wo2 only (64 KB) ------------
__global__ __launch_bounds__(256, 2) void fused_kernel(
    const float* __restrict__ obs, const float* __restrict__ act,
    const uint32_t* __restrict__ cntp,
    const uint16_t* __restrict__ W1F, const uint16_t* __restrict__ W2F,
    const float* __restrict__ b1, const float* __restrict__ b2,
    const uint16_t* __restrict__ Wo1F, const float* __restrict__ bo1,
    const float* __restrict__ g1, const float* __restrict__ be1,
    const uint16_t* __restrict__ Wo2F, const float* __restrict__ bo2,
    const float* __restrict__ g2, const float* __restrict__ be2,
    const float* __restrict__ Wo3, const float* __restrict__ bo3,
    const float* __restrict__ wvec, float* __restrict__ out)
{
  __shared__ __align__(16) uint16_t Wo2s[32768];   // exactly 64 KB -> 2 blocks/CU
  const int tid = threadIdx.x;
  {
    uint4* d3 = (uint4*)Wo2s; const uint4* s3 = (const uint4*)Wo2F;
    #pragma unroll
    for (int i = 0; i < 16; ++i) d3[tid + 256 * i] = s3[tid + 256 * i];
  }
  // NOTE: no barrier here — the only __syncthreads() is before MLP1; staging
  // latency hides under the whole GAT phase.

  const int l = tid & 63, hi = l >> 5, col = l & 31;
  const int wid = blockIdx.x * 4 + (tid >> 6);
  const int e = wid * 32 + col;
  const uint32_t cp = cntp[e];
  const float* obs_e = obs + (size_t)e * 90;
  const float* act_e = act + (size_t)e * 15;

  // ===== GAT layer 1 (+ per-lane score dots in f32) =====
  f32x16 az[3][2];
  #pragma unroll
  for (int n = 0; n < 3; ++n)
    #pragma unroll
    for (int t = 0; t < 2; ++t)
      #pragma unroll
      for (int r = 0; r < 16; ++r) az[n][t][r] = 0.f;
  float ss1[3] = {0, 0, 0}, sd1[3] = {0, 0, 0};

  #pragma unroll
  for (int ks = 0; ks < 3; ++ks) {
    bf8 xh[3], xl[3];
    #pragma unroll
    for (int n = 0; n < 3; ++n) {
      const float* on = obs_e + n * 30;
      float xv[8];
      #pragma unroll
      for (int r2 = 0; r2 < 2; ++r2) {
        if (ks == 2 && r2 == 1) { xv[4] = xv[5] = xv[6] = xv[7] = 0.f; continue; }
        const int kb = ks * 16 + r2 * 8 + hi * 4;
        #pragma unroll
        for (int j = 0; j < 4; ++j) {
          const int k = kb + j;
          float v = 0.f;
          if (k < 30) v = on[k];
          else if (k < 35) v = act_e[n * 5 + k - 30];
          xv[r2 * 4 + j] = v;
        }
        // score dot vs W1@a vectors (f32)
        float4 s4 = *reinterpret_cast<const float4*>(wvec + kb);
        float4 d4 = *reinterpret_cast<const float4*>(wvec + 64 + kb);
        ss1[n] = fmaf(xv[r2 * 4 + 0], s4.x, ss1[n]); sd1[n] = fmaf(xv[r2 * 4 + 0], d4.x, sd1[n]);
        ss1[n] = fmaf(xv[r2 * 4 + 1], s4.y, ss1[n]); sd1[n] = fmaf(xv[r2 * 4 + 1], d4.y, sd1[n]);
        ss1[n] = fmaf(xv[r2 * 4 + 2], s4.z, ss1[n]); sd1[n] = fmaf(xv[r2 * 4 + 2], d4.z, sd1[n]);
        ss1[n] = fmaf(xv[r2 * 4 + 3], s4.w, ss1[n]); sd1[n] = fmaf(xv[r2 * 4 + 3], d4.w, sd1[n]);
      }
      uint32_t hw[4], lw[4];
      #pragma unroll
      for (int p = 0; p < 4; ++p) {
        hw[p] = pkbf(xv[2 * p], xv[2 * p + 1]);
        float ra = xv[2 * p]     - bf2f(hw[p]);
        float rb = xv[2 * p + 1] - bfhi2f(hw[p]);
        lw[p] = (__float_as_uint(ra) >> 16) | (__float_as_uint(rb) & 0xffff0000u);
      }
      xh[n] = mkfrag(hw[0], hw[1], hw[2], hw[3]);
      xl[n] = mkfrag(lw[0], lw[1], lw[2], lw[3]);
    }
    #pragma unroll
    for (int t = 0; t < 2; ++t) {
      bf8 a = *reinterpret_cast<const bf8*>(W1F + (size_t)((ks * 2 + t) * 64 + l) * 8);
      #pragma unroll
      for (int n = 0; n < 3; ++n) {
        az[n][t] = __builtin_amdgcn_mfma_f32_32x32x16_bf16(a, xh[n], az[n][t], 0, 0, 0);
        az[n][t] = __builtin_amdgcn_mfma_f32_32x32x16_bf16(a, xl[n], az[n][t], 0, 0, 0);
      }
    }
  }
  #pragma unroll
  for (int n = 0; n < 3; ++n) {
    ss1[n] += __shfl_xor(ss1[n], 32);
    sd1[n] += __shfl_xor(sd1[n], 32);
  }

  uint32_t Ph1[3][16];
  float ss2[3] = {0, 0, 0}, sd2[3] = {0, 0, 0};
  attention<true, true>(az, ss1, sd1, cp, hi, b1, wvec + 128, wvec + 192, Ph1, ss2, sd2);
  #pragma unroll
  for (int n = 0; n < 3; ++n) {
    ss2[n] += __shfl_xor(ss2[n], 32);
    sd2[n] += __shfl_xor(sd2[n], 32);
  }

  // ===== GAT layer 2 =====
  f32x16 a2[3][2];
  #pragma unroll
  for (int n = 0; n < 3; ++n)
    #pragma unroll
    for (int t = 0; t < 2; ++t)
      #pragma unroll
      for (int r = 0; r < 16; ++r) a2[n][t][r] = 0.f;
  #pragma unroll
  for (int ks = 0; ks < 4; ++ks) {
    #pragma unroll
    for (int t = 0; t < 2; ++t) {
      bf8 a = *reinterpret_cast<const bf8*>(W2F + (size_t)((ks * 2 + t) * 64 + l) * 8);
      #pragma unroll
      for (int n = 0; n < 3; ++n) {
        bf8 br_ = mkfrag(Ph1[n][4 * ks], Ph1[n][4 * ks + 1], Ph1[n][4 * ks + 2], Ph1[n][4 * ks + 3]);
        a2[n][t] = __builtin_amdgcn_mfma_f32_32x32x16_bf16(a, br_, a2[n][t], 0, 0, 0);
      }
    }
  }

  uint32_t Ph2[3][16];
  float du1[3], du2[3];
  attention<false, false>(a2, ss2, sd2, cp, hi, b2, nullptr, nullptr, Ph2, du1, du2);

  __syncthreads();   // Wo2s staging fence + align block's waves for the Wo1F stream

  // ===== MLP layer 1: two halves of 128 features; pre-LN bf16 pack =====
  float sm = 0.f, sq = 0.f;
  uint32_t y[64];
  #pragma unroll
  for (int half = 0; half < 2; ++half) {
    f32x16 acc[4];
    #pragma unroll
    for (int t = 0; t < 4; ++t)
      #pragma unroll
      for (int rq = 0; rq < 4; ++rq) {
        float4 b4 = *reinterpret_cast<const float4*>(bo1 + (half * 4 + t) * 32 + rq * 8 + hi * 4);
        acc[t][4 * rq + 0] = b4.x; acc[t][4 * rq + 1] = b4.y;
        acc[t][4 * rq + 2] = b4.z; acc[t][4 * rq + 3] = b4.w;
      }
    #pragma unroll
    for (int ks = 0; ks < 12; ++ks) {
      const int n = ks >> 2, q0 = 4 * (ks & 3);
      bf8 br_ = mkfrag(Ph2[n][q0], Ph2[n][q0 + 1], Ph2[n][q0 + 2], Ph2[n][q0 + 3]);
      #pragma unroll
      for (int t = 0; t < 4; ++t) {
        bf8 a = *reinterpret_cast<const bf8*>(Wo1F + (size_t)((ks * 8 + half * 4 + t) * 64 + l) * 8);
        acc[t] = __builtin_amdgcn_mfma_f32_32x32x16_bf16(a, br_, acc[t], 0, 0, 0);
      }
    }
    #pragma unroll
    for (int t = 0; t < 4; ++t) {
      #pragma unroll
      for (int r = 0; r < 16; ++r) { const float v = acc[t][r]; sm += v; sq = fmaf(v, v, sq); }
      #pragma unroll
      for (int p = 0; p < 8; ++p)
        y[(half * 4 + t) * 8 + p] = pkbf(acc[t][2 * p], acc[t][2 * p + 1]);
    }
  }
  sm += __shfl_xor(sm, 32); sq += __shfl_xor(sq, 32);
  float mu = sm * (1.f / 256.f);
  float rr = rsqrtf(sq * (1.f / 256.f) - mu * mu + 1e-5f);
  #pragma unroll
  for (int tg = 0; tg < 8; ++tg)
    #pragma unroll
    for (int rq = 0; rq < 4; ++rq) {
      float4 gg = *reinterpret_cast<const float4*>(g1 + tg * 32 + rq * 8 + hi * 4);
      float4 bb = *reinterpret_cast<const float4*>(be1 + tg * 32 + rq * 8 + hi * 4);
      const int w0 = tg * 8 + rq * 2;
      float v0 = (bf2f(y[w0]) - mu) * rr * gg.x + bb.x;        v0 = fmaxf(v0, 0.01f * v0);
      float v1 = (bfhi2f(y[w0]) - mu) * rr * gg.y + bb.y;      v1 = fmaxf(v1, 0.01f * v1);
      y[w0] = pkbf(v0, v1);
      float v2 = (bf2f(y[w0 + 1]) - mu) * rr * gg.z + bb.z;    v2 = fmaxf(v2, 0.01f * v2);
      float v3 = (bfhi2f(y[w0 + 1]) - mu) * rr * gg.w + bb.w;  v3 = fmaxf(v3, 0.01f * v3);
      y[w0 + 1] = pkbf(v2, v3);
    }

  // ===== MLP layer 2 (Wo2 from LDS) =====
  f32x16 acc2[4];
  #pragma unroll
  for (int t = 0; t < 4; ++t)
    #pragma unroll
    for (int rq = 0; rq < 4; ++rq) {
      float4 b4 = *reinterpret_cast<const float4*>(bo2 + t * 32 + rq * 8 + hi * 4);
      acc2[t][4 * rq + 0] = b4.x; acc2[t][4 * rq + 1] = b4.y;
      acc2[t][4 * rq + 2] = b4.z; acc2[t][4 * rq + 3] = b4.w;
    }
  #pragma unroll
  for (int ks = 0; ks < 16; ++ks) {
    bf8 br_ = mkfrag(y[4 * ks], y[4 * ks + 1], y[4 * ks + 2], y[4 * ks + 3]);
    #pragma unroll
    for (int t = 0; t < 4; ++t) {
      bf8 a = *reinterpret_cast<const bf8*>(&Wo2s[(ks * 4 + t) * 512 + l * 8]);
      acc2[t] = __builtin_amdgcn_mfma_f32_32x32x16_bf16(a, br_, acc2[t], 0, 0, 0);
    }
  }
  // LN(128) + lrelu + final dot with Wo3
  sm = 0.f; sq = 0.f;
  #pragma unroll
  for (int t = 0; t < 4; ++t)
    #pragma unroll
    for (int r = 0; r < 16; ++r) { const float v = acc2[t][r]; sm += v; sq = fmaf(v, v, sq); }
  sm += __shfl_xor(sm, 32); sq += __shfl_xor(sq, 32);
  mu = sm * (1.f / 128.f);
  rr = rsqrtf(sq * (1.f / 128.f) - mu * mu + 1e-5f);
  float acy = 0.f;
  #pragma unroll
  for (int t = 0; t < 4; ++t)
    #pragma unroll
    for (int rq = 0; rq < 4; ++rq) {
      float4 gg = *reinterpret_cast<const float4*>(g2 + t * 32 + rq * 8 + hi * 4);
      float4 bb = *reinterpret_cast<const float4*>(be2 + t * 32 + rq * 8 + hi * 4);
      float4 ww = *reinterpret_cast<const float4*>(Wo3 + t * 32 + rq * 8 + hi * 4);
      float v;
      v = (acc2[t][4 * rq + 0] - mu) * rr * gg.x + bb.x; acy = fmaf(fmaxf(v, 0.01f * v), ww.x, acy);
      v = (acc2[t][4 * rq + 1] - mu) * rr * gg.y + bb.y; acy = fmaf(fmaxf(v, 0.01f * v), ww.y, acy);
      v = (acc2[t][4 * rq + 2] - mu) * rr * gg.z + bb.z; acy = fmaf(fmaxf(v, 0.01f * v), ww.z, acy);
      v = (acc2[t][4 * rq + 3] - mu) * rr * gg.w + bb.w; acy = fmaf(fmaxf(v, 0.01f * v), ww.w, acy);
    }
  acy += __shfl_xor(acy, 32);
  if (hi == 0) out[e] = acy + bo3[0];
}

extern "C" void kernel_launch(void* const* d_in, const int* in_sizes, int n_in,
                              void* d_out, int out_size, void* d_ws, size_t ws_size,
                              hipStream_t stream) {
  const float* obs  = (const float*)d_in[0];
  const float* actn = (const float*)d_in[1];
  const int*   adj  = (const int*)d_in[2];
  const float* W1   = (const float*)d_in[3];
  const float* a1s  = (const float*)d_in[4];
  const float* a1d  = (const float*)d_in[5];
  const float* b1   = (const float*)d_in[6];
  const float* W2   = (const float*)d_in[7];
  const float* a2s  = (const float*)d_in[8];
  const float* a2d  = (const float*)d_in[9];
  const float* b2   = (const float*)d_in[10];
  const float* Wo1  = (const float*)d_in[11];
  const float* bo1  = (const float*)d_in[12];
  const float* g1   = (const float*)d_in[13];
  const float* be1  = (const float*)d_in[14];
  const float* Wo2  = (const float*)d_in[15];
  const float* bo2  = (const float*)d_in[16];
  const float* g2   = (const float*)d_in[17];
  const float* be2  = (const float*)d_in[18];
  const float* Wo3  = (const float*)d_in[19];
  const float* bo3  = (const float*)d_in[20];

  char* ws = (char*)d_ws;
  uint32_t* cntp = (uint32_t*)ws;                       // 1 MB
  uint16_t* W1F  = (uint16_t*)(ws + 1048576);           // 6144 B
  uint16_t* W2F  = (uint16_t*)(ws + 1048576 + 8192);    // 8192 B
  uint16_t* Wo1F = (uint16_t*)(ws + 1048576 + 16384);   // 98304 B
  uint16_t* Wo2F = (uint16_t*)(ws + 1048576 + 114688);  // 65536 B
  float*    wvec = (float*)(ws + 1048576 + 180224);     // 1024 B
  float* outp = (float*)d_out;

  prep_kernel<<<1024, 256, 0, stream>>>(adj, W1, a1s, a1d, W2, a2s, a2d, Wo1, Wo2,
                                        cntp, W1F, W2F, Wo1F, Wo2F, wvec);
  fused_kernel<<<2048, 256, 0, stream>>>(obs, actn, cntp, W1F, W2F, b1, b2,
                                         Wo1F, bo1, g1, be1, Wo2F, bo2, g2, be2,
                                         Wo3, bo3, wvec, outp);
}